// Round 5
// baseline (283.566 us; speedup 1.0000x reference)
//
#include <hip/hip_runtime.h>

typedef __bf16 bf16x8 __attribute__((ext_vector_type(8)));
typedef short  s16x8  __attribute__((ext_vector_type(8)));
typedef float  f32x4  __attribute__((ext_vector_type(4)));

#define DEVINL __device__ __forceinline__

DEVINL unsigned short f2bf(float f) {
  unsigned int u = __builtin_bit_cast(unsigned int, f);
  u += 0x7fffu + ((u >> 16) & 1u);   // round-to-nearest-even
  return (unsigned short)(u >> 16);
}

DEVINL void async16(const void* g, void* l) {
  __builtin_amdgcn_global_load_lds(
      (const __attribute__((address_space(1))) unsigned int*)g,
      (__attribute__((address_space(3))) unsigned int*)l, 16, 0, 0);
}

// ---------------- conversion kernels ----------------

__global__ void cvt_f32_bf16(const float* __restrict__ in,
                             unsigned short* __restrict__ out, int n4) {
  int i = blockIdx.x * blockDim.x + threadIdx.x;
  int stride = gridDim.x * blockDim.x;
  for (; i < n4; i += stride) {
    float4 v = ((const float4*)in)[i];
    ushort4 o;
    o.x = f2bf(v.x); o.y = f2bf(v.y); o.z = f2bf(v.z); o.w = f2bf(v.w);
    ((ushort4*)out)[i] = o;
  }
}

// in: [R][C] fp32  ->  out: [C][R] bf16
__global__ void transpose_cvt(const float* __restrict__ in,
                              unsigned short* __restrict__ out, int R, int C) {
  __shared__ unsigned short tile[32][33];
  int bc = blockIdx.x * 32, br = blockIdx.y * 32;
  int tx = threadIdx.x & 31, ty = threadIdx.x >> 5;
#pragma unroll
  for (int i = 0; i < 32; i += 8)
    tile[ty + i][tx] = f2bf(in[(size_t)(br + ty + i) * C + (bc + tx)]);
  __syncthreads();
#pragma unroll
  for (int i = 0; i < 32; i += 8)
    out[(size_t)(bc + ty + i) * R + (br + tx)] = tile[tx][ty + i];
}

__global__ void qconst(const float* __restrict__ theta,
                       const float* __restrict__ wre,
                       const float* __restrict__ wim,
                       float* __restrict__ c1, int n) {
  int i = blockIdx.x * blockDim.x + threadIdx.x;
  if (i < n) {
    float t = theta[i];
    c1[i] = (cosf(t) * wre[i] + sinf(t) * wim[i]) * wim[i] * 0.1f;
  }
}

// ---------- skewed-pipeline GEMM: C = A[M][K] * Bt[N][K]^T ----------
// BMxBN tile, BK=64, 8 waves (2M x 4N), double-buffered LDS, XOR swizzle.
// 2 windows (=2 barriers) per K-tile; every MFMA cluster consumes fragments
// loaded in a PREVIOUS window so no cluster waits on this window's ds_reads:
//   WIN_A(T): read b0,b1,a1(T); Q00,Q01 use a0 (preloaded in WIN_B(T-1)).
//             lgkm0 (my reads done -> others may overwrite after BAR);
//             vmcnt(0) certifies tile T+1 (staged in WIN_B(T-1)); BAR.
//   WIN_B(T): stage A,B(T+2)->buf(T)   [A region: a0(T) read in B(T-1),
//             a1(T) read in A(T), both drained before A(T)'s BAR; B region:
//             b(T) read in A(T), drained likewise -> regions free];
//             read a0(T+1) from buf(T+1) [certified by A(T)'s vmcnt(0)];
//             Q10,Q11 use a1,b (all in registers). lgkm0; BAR.
// Register sets are single-buffered by construction:
//   a0: loaded WIN_B(T) -> used WIN_A(T+1);  a1: loaded WIN_A(T) -> WIN_B(T);
//   b : loaded WIN_A(T) -> used A(T)+B(T), reloaded next tile.

template <int BM, int BN, int NT, bool FUSED>
__global__ __launch_bounds__(512, 2) void gemmsk(
    const unsigned short* __restrict__ A,
    const unsigned short* __restrict__ Bt,
    const float* __restrict__ bias,
    const float* __restrict__ theta,
    const float* __restrict__ c1,
    void* __restrict__ Cout,
    int N, int nTilesN) {
  constexpr int K      = NT * 64;
  constexpr int WROWS  = BM / 2;        // per-wave output rows
  constexpr int M_REP  = WROWS / 16;    // 8 (BM=256) or 4 (BM=128)
  constexpr int MH     = M_REP / 2;
  constexpr int ABYTES = BM * 128;      // A region bytes per buffer
  constexpr int BUF    = (BM + BN) * 128;
  constexpr int LA     = ABYTES / 8192; // per-thread A stage-loads per K-tile
  constexpr int LB     = BN * 128 / 8192;
  static_assert(LB == 4 && (LA == 4 || LA == 2), "geometry");

  __shared__ __align__(16) char lds[2 * BUF];

  // bijective XCD swizzle (grid % 8 == 0 for both instantiations)
  int nwg = gridDim.x;
  int wg = blockIdx.x;
  int sw = (wg & 7) * (nwg >> 3) + (wg >> 3);
  int rowBase = (sw / nTilesN) * BM;
  int colBase = (sw % nTilesN) * BN;

  const int t = threadIdx.x;
  const int lane = t & 63;
  const int wid = t >> 6;
  const int wr = wid >> 2, wc = wid & 3;   // 2M x 4N waves
  const int lr = lane & 15;
  const int lg = lane >> 4;                // 0..3
  const int r7 = lane & 7;

  // staging source (pre-swizzled global address, linear LDS dest)
  const int arow = t >> 3;                             // 0..63
  const int acolB = ((t & 7) * 16) ^ ((arow & 7) << 4);
  const unsigned short* aSrc = A  + (size_t)(rowBase + arow) * K + (acolB >> 1);
  const unsigned short* bSrc = Bt + (size_t)(colBase + arow) * K + (acolB >> 1);

  // swizzled ds_read bases (bytes); frag i: +i*2048, ks: ^ (ks*64)
  const int aRd = (wr * WROWS + lr) * 128 + ((lg ^ r7) * 16);
  const int bRd = ABYTES + (wc * 64 + lr) * 128 + ((lg ^ r7) * 16);

  f32x4 acc[M_REP][4] = {};
  bf16x8 a0[MH][2], a1[MH][2], b[4][2];

#define STAGE_A(T1, BO, j)                                                  \
  async16(aSrc + ((size_t)(j) * 64 * K + (size_t)(T1) * 64),                \
          &lds[(BO) + (j) * 8192 + t * 16])
#define STAGE_B(T2, BO, j)                                                  \
  async16(bSrc + ((size_t)(j) * 64 * K + (size_t)(T2) * 64),                \
          &lds[(BO) + ABYTES + (j) * 8192 + t * 16])

#define LDS_B2(nh, BO)                                                      \
  _Pragma("unroll") for (int nn = 0; nn < 2; ++nn)                          \
  _Pragma("unroll") for (int ks = 0; ks < 2; ++ks)                          \
    b[(nh) * 2 + nn][ks] = __builtin_bit_cast(bf16x8, *(const s16x8*)&lds[  \
        (BO) + ((bRd + ((nh) * 2 + nn) * 2048) ^ (ks * 64))])
#define LDS_A0(BO)                                                          \
  _Pragma("unroll") for (int mi = 0; mi < MH; ++mi)                         \
  _Pragma("unroll") for (int ks = 0; ks < 2; ++ks)                          \
    a0[mi][ks] = __builtin_bit_cast(bf16x8, *(const s16x8*)&lds[            \
        (BO) + ((aRd + mi * 2048) ^ (ks * 64))])
#define LDS_A1(BO)                                                          \
  _Pragma("unroll") for (int mi = 0; mi < MH; ++mi)                         \
  _Pragma("unroll") for (int ks = 0; ks < 2; ++ks)                          \
    a1[mi][ks] = __builtin_bit_cast(bf16x8, *(const s16x8*)&lds[            \
        (BO) + ((aRd + (MH + mi) * 2048) ^ (ks * 64))])

#define QUAD(AF, MOFF, nh)                                                  \
  __builtin_amdgcn_s_setprio(1);                                            \
  _Pragma("unroll") for (int mi = 0; mi < MH; ++mi)                         \
  _Pragma("unroll") for (int nn = 0; nn < 2; ++nn)                          \
  _Pragma("unroll") for (int ks = 0; ks < 2; ++ks)                          \
    acc[(MOFF) + mi][(nh) * 2 + nn] =                                       \
        __builtin_amdgcn_mfma_f32_16x16x32_bf16(                            \
            AF[mi][ks], b[(nh) * 2 + nn][ks],                               \
            acc[(MOFF) + mi][(nh) * 2 + nn], 0, 0, 0);                      \
  __builtin_amdgcn_s_setprio(0)

#define BAR() __builtin_amdgcn_s_barrier()
#define DRAIN_LGKM() asm volatile("s_waitcnt lgkmcnt(0)" ::: "memory")
#define DRAIN_VM() asm volatile("s_waitcnt vmcnt(0)" ::: "memory")

#define WIN_A(T, BO) do {                                                   \
    LDS_B2(0, BO);                                                          \
    LDS_B2(1, BO);                                                          \
    LDS_A1(BO);                                                             \
    QUAD(a0, 0, 0);                                                         \
    QUAD(a0, 0, 1);                                                         \
    DRAIN_LGKM();                                                           \
    DRAIN_VM();                                                             \
    BAR();                                                                  \
  } while (0)

#define WIN_B(T, BO, OBO) do {                                              \
    if ((T) + 2 < NT) {                                                     \
      _Pragma("unroll") for (int j = 0; j < LA; ++j)                        \
        STAGE_A((T) + 2, BO, j);                                            \
      _Pragma("unroll") for (int j = 0; j < LB; ++j)                        \
        STAGE_B((T) + 2, BO, j);                                            \
    }                                                                       \
    if ((T) + 1 < NT) LDS_A0(OBO);                                          \
    QUAD(a1, MH, 0);                                                        \
    QUAD(a1, MH, 1);                                                        \
    DRAIN_LGKM();                                                           \
    BAR();                                                                  \
  } while (0)

  // prologue: stage tiles 0 and 1; certify tile 0; preload a0(0)
#pragma unroll
  for (int j = 0; j < LA; ++j) STAGE_A(0, 0, j);
#pragma unroll
  for (int j = 0; j < LB; ++j) STAGE_B(0, 0, j);
#pragma unroll
  for (int j = 0; j < LA; ++j) STAGE_A(1, BUF, j);
#pragma unroll
  for (int j = 0; j < LB; ++j) STAGE_B(1, BUF, j);
  asm volatile("s_waitcnt vmcnt(%0)" :: "n"(LA + LB) : "memory");
  BAR();
  LDS_A0(0);

  for (int T = 0; T < NT; T += 2) {
    WIN_A(T, 0);
    WIN_B(T, 0, BUF);
    WIN_A(T + 1, BUF);
    WIN_B(T + 1, BUF, 0);
  }

#undef WIN_A
#undef WIN_B
#undef QUAD
#undef LDS_A0
#undef LDS_A1
#undef LDS_B2
#undef STAGE_A
#undef STAGE_B
#undef BAR
#undef DRAIN_LGKM
#undef DRAIN_VM

  // epilogue
  const int orow0 = rowBase + wr * WROWS + (lane >> 4) * 4;
  const int ocol0 = colBase + wc * 64 + lr;
#pragma unroll
  for (int ni = 0; ni < 4; ++ni) {
    int n = ocol0 + ni * 16;
    float bv = bias[n];
    float th = 0.f, cc = 0.f;
    if constexpr (FUSED) { th = theta[n]; cc = c1[n]; }
#pragma unroll
    for (int mi = 0; mi < M_REP; ++mi) {
#pragma unroll
      for (int r = 0; r < 4; ++r) {
        size_t m = (size_t)(orow0 + mi * 16 + r);
        float h = acc[mi][ni][r] + bv;
        if constexpr (FUSED) {
          float q = h + cc * __sinf(th + 0.1f * h);
          ((unsigned short*)Cout)[m * N + n] = f2bf(fmaxf(q, 0.f));
        } else {
          ((float*)Cout)[m * N + n] = h;
        }
      }
    }
  }
}

// ---------------- launch ----------------

extern "C" void kernel_launch(void* const* d_in, const int* in_sizes, int n_in,
                              void* d_out, int out_size, void* d_ws,
                              size_t ws_size, hipStream_t stream) {
  const float* x     = (const float*)d_in[0];
  const float* W1    = (const float*)d_in[1];
  const float* b1    = (const float*)d_in[2];
  const float* theta = (const float*)d_in[3];
  const float* qwr   = (const float*)d_in[4];
  const float* qwi   = (const float*)d_in[5];
  const float* W2    = (const float*)d_in[6];
  const float* b2    = (const float*)d_in[7];
  float* out = (float*)d_out;

  const int M = 4 * 2048;            // 8192
  const int DM = 1024, DF = 4096;

  size_t need = ((size_t)96 << 20) + DF * sizeof(float);
  if (ws_size < need) return;

  char* ws = (char*)d_ws;
  unsigned short* xb   = (unsigned short*)ws;                          // 16 MiB
  unsigned short* w1t  = (unsigned short*)(ws + ((size_t)16 << 20));   //  8 MiB
  unsigned short* w2t  = (unsigned short*)(ws + ((size_t)24 << 20));   //  8 MiB
  unsigned short* actb = (unsigned short*)(ws + ((size_t)32 << 20));   // 64 MiB
  float* c1 = (float*)(ws + ((size_t)96 << 20));

  cvt_f32_bf16<<<2048, 256, 0, stream>>>(x, xb, M * DM / 4);
  transpose_cvt<<<dim3(DF / 32, DM / 32), 256, 0, stream>>>(W1, w1t, DM, DF);
  transpose_cvt<<<dim3(DM / 32, DF / 32), 256, 0, stream>>>(W2, w2t, DF, DM);
  qconst<<<DF / 256, 256, 0, stream>>>(theta, qwr, qwi, c1, DF);

  // GEMM1: 8192x4096, K=1024 -> 512 blocks (256x256 tile)
  gemmsk<256, 256, 16, true><<<512, 512, 0, stream>>>(
      xb, w1t, b1, theta, c1, (void*)actb, DF, DF / 256);
  // GEMM2: 8192x1024, K=4096 -> 256 blocks (128x256 tile)
  gemmsk<128, 256, 64, false><<<256, 512, 0, stream>>>(
      actb, w2t, b2, nullptr, nullptr, (void*)out, DM, DM / 256);
}

// Round 6
// 281.721 us; speedup vs baseline: 1.0065x; 1.0065x over previous
//
#include <hip/hip_runtime.h>

typedef __bf16 bf16x8 __attribute__((ext_vector_type(8)));
typedef short  s16x8  __attribute__((ext_vector_type(8)));
typedef float  f32x4  __attribute__((ext_vector_type(4)));

#define DEVINL __device__ __forceinline__

DEVINL unsigned short f2bf(float f) {
  unsigned int u = __builtin_bit_cast(unsigned int, f);
  u += 0x7fffu + ((u >> 16) & 1u);   // round-to-nearest-even
  return (unsigned short)(u >> 16);
}

DEVINL void async16(const void* g, void* l) {
  __builtin_amdgcn_global_load_lds(
      (const __attribute__((address_space(1))) unsigned int*)g,
      (__attribute__((address_space(3))) unsigned int*)l, 16, 0, 0);
}

// ---------------- conversion kernels ----------------

__global__ void cvt_f32_bf16(const float* __restrict__ in,
                             unsigned short* __restrict__ out, int n4) {
  int i = blockIdx.x * blockDim.x + threadIdx.x;
  int stride = gridDim.x * blockDim.x;
  for (; i < n4; i += stride) {
    float4 v = ((const float4*)in)[i];
    ushort4 o;
    o.x = f2bf(v.x); o.y = f2bf(v.y); o.z = f2bf(v.z); o.w = f2bf(v.w);
    ((ushort4*)out)[i] = o;
  }
}

// in: [R][C] fp32  ->  out: [C][R] bf16
__global__ void transpose_cvt(const float* __restrict__ in,
                              unsigned short* __restrict__ out, int R, int C) {
  __shared__ unsigned short tile[32][33];
  int bc = blockIdx.x * 32, br = blockIdx.y * 32;
  int tx = threadIdx.x & 31, ty = threadIdx.x >> 5;
#pragma unroll
  for (int i = 0; i < 32; i += 8)
    tile[ty + i][tx] = f2bf(in[(size_t)(br + ty + i) * C + (bc + tx)]);
  __syncthreads();
#pragma unroll
  for (int i = 0; i < 32; i += 8)
    out[(size_t)(bc + ty + i) * R + (br + tx)] = tile[tx][ty + i];
}

__global__ void qconst(const float* __restrict__ theta,
                       const float* __restrict__ wre,
                       const float* __restrict__ wim,
                       float* __restrict__ c1, int n) {
  int i = blockIdx.x * blockDim.x + threadIdx.x;
  if (i < n) {
    float t = theta[i];
    c1[i] = (cosf(t) * wre[i] + sinf(t) * wim[i]) * wim[i] * 0.1f;
  }
}

// ---------- skewed-pipeline GEMM: C = A[M][K] * Bt[N][K]^T ----------
// BMxBN tile, BK=64, 8 waves (2M x 4N), double-buffered LDS, XOR swizzle.
// 2 windows (=2 barriers) per K-tile; every MFMA cluster consumes fragments
// loaded in a PREVIOUS window so no cluster waits on this window's ds_reads:
//   WIN_A(T): read b0,b1,a1(T); Q00,Q01 use a0 (preloaded in WIN_B(T-1)).
//             lgkm0 (my reads done -> others may overwrite after BAR);
//             vmcnt(0) certifies tile T+1 (staged in WIN_B(T-1)); BAR.
//   WIN_B(T): stage A,B(T+2)->buf(T)   [A region: a0(T) read in B(T-1),
//             a1(T) read in A(T), both drained before A(T)'s BAR; B region:
//             b(T) read in A(T), drained likewise -> regions free];
//             read a0(T+1) from buf(T+1) [certified by A(T)'s vmcnt(0)];
//             Q10,Q11 use a1,b (all in registers). lgkm0; BAR.
// Register sets are single-buffered by construction:
//   a0: loaded WIN_B(T) -> used WIN_A(T+1);  a1: loaded WIN_A(T) -> WIN_B(T);
//   b : loaded WIN_A(T) -> used A(T)+B(T), reloaded next tile.

template <int BM, int BN, int NT, bool FUSED>
__global__ __launch_bounds__(512, 2) void gemmsk(
    const unsigned short* __restrict__ A,
    const unsigned short* __restrict__ Bt,
    const float* __restrict__ bias,
    const float* __restrict__ theta,
    const float* __restrict__ c1,
    void* __restrict__ Cout,
    int N, int nTilesN) {
  constexpr int K      = NT * 64;
  constexpr int WROWS  = BM / 2;        // per-wave output rows
  constexpr int M_REP  = WROWS / 16;    // 8 (BM=256) or 4 (BM=128)
  constexpr int MH     = M_REP / 2;
  constexpr int ABYTES = BM * 128;      // A region bytes per buffer
  constexpr int BUF    = (BM + BN) * 128;
  constexpr int LA     = ABYTES / 8192; // per-thread A stage-loads per K-tile
  constexpr int LB     = BN * 128 / 8192;
  static_assert(LB == 4 && (LA == 4 || LA == 2), "geometry");

  __shared__ __align__(16) char lds[2 * BUF];

  // bijective XCD swizzle (grid % 8 == 0 for both instantiations)
  int nwg = gridDim.x;
  int wg = blockIdx.x;
  int sw = (wg & 7) * (nwg >> 3) + (wg >> 3);
  int rowBase = (sw / nTilesN) * BM;
  int colBase = (sw % nTilesN) * BN;

  const int t = threadIdx.x;
  const int lane = t & 63;
  const int wid = t >> 6;
  const int wr = wid >> 2, wc = wid & 3;   // 2M x 4N waves
  const int lr = lane & 15;
  const int lg = lane >> 4;                // 0..3
  const int r7 = lane & 7;

  // staging source (pre-swizzled global address, linear LDS dest)
  const int arow = t >> 3;                             // 0..63
  const int acolB = ((t & 7) * 16) ^ ((arow & 7) << 4);
  const unsigned short* aSrc = A  + (size_t)(rowBase + arow) * K + (acolB >> 1);
  const unsigned short* bSrc = Bt + (size_t)(colBase + arow) * K + (acolB >> 1);

  // swizzled ds_read bases (bytes); frag i: +i*2048, ks: ^ (ks*64)
  const int aRd = (wr * WROWS + lr) * 128 + ((lg ^ r7) * 16);
  const int bRd = ABYTES + (wc * 64 + lr) * 128 + ((lg ^ r7) * 16);

  f32x4 acc[M_REP][4] = {};
  bf16x8 a0[MH][2], a1[MH][2], b[4][2];

#define STAGE_A(T1, BO, j)                                                  \
  async16(aSrc + ((size_t)(j) * 64 * K + (size_t)(T1) * 64),                \
          &lds[(BO) + (j) * 8192 + t * 16])
#define STAGE_B(T2, BO, j)                                                  \
  async16(bSrc + ((size_t)(j) * 64 * K + (size_t)(T2) * 64),                \
          &lds[(BO) + ABYTES + (j) * 8192 + t * 16])

#define LDS_B2(nh, BO)                                                      \
  _Pragma("unroll") for (int nn = 0; nn < 2; ++nn)                          \
  _Pragma("unroll") for (int ks = 0; ks < 2; ++ks)                          \
    b[(nh) * 2 + nn][ks] = __builtin_bit_cast(bf16x8, *(const s16x8*)&lds[  \
        (BO) + ((bRd + ((nh) * 2 + nn) * 2048) ^ (ks * 64))])
#define LDS_A0(BO)                                                          \
  _Pragma("unroll") for (int mi = 0; mi < MH; ++mi)                         \
  _Pragma("unroll") for (int ks = 0; ks < 2; ++ks)                          \
    a0[mi][ks] = __builtin_bit_cast(bf16x8, *(const s16x8*)&lds[            \
        (BO) + ((aRd + mi * 2048) ^ (ks * 64))])
#define LDS_A1(BO)                                                          \
  _Pragma("unroll") for (int mi = 0; mi < MH; ++mi)                         \
  _Pragma("unroll") for (int ks = 0; ks < 2; ++ks)                          \
    a1[mi][ks] = __builtin_bit_cast(bf16x8, *(const s16x8*)&lds[            \
        (BO) + ((aRd + (MH + mi) * 2048) ^ (ks * 64))])

#define QUAD(AF, MOFF, nh)                                                  \
  __builtin_amdgcn_s_setprio(1);                                            \
  _Pragma("unroll") for (int mi = 0; mi < MH; ++mi)                         \
  _Pragma("unroll") for (int nn = 0; nn < 2; ++nn)                          \
  _Pragma("unroll") for (int ks = 0; ks < 2; ++ks)                          \
    acc[(MOFF) + mi][(nh) * 2 + nn] =                                       \
        __builtin_amdgcn_mfma_f32_16x16x32_bf16(                            \
            AF[mi][ks], b[(nh) * 2 + nn][ks],                               \
            acc[(MOFF) + mi][(nh) * 2 + nn], 0, 0, 0);                      \
  __builtin_amdgcn_s_setprio(0)

#define BAR() __builtin_amdgcn_s_barrier()
#define DRAIN_LGKM() asm volatile("s_waitcnt lgkmcnt(0)" ::: "memory")
#define DRAIN_VM() asm volatile("s_waitcnt vmcnt(0)" ::: "memory")

#define WIN_A(T, BO) do {                                                   \
    LDS_B2(0, BO);                                                          \
    LDS_B2(1, BO);                                                          \
    LDS_A1(BO);                                                             \
    QUAD(a0, 0, 0);                                                         \
    QUAD(a0, 0, 1);                                                         \
    DRAIN_LGKM();                                                           \
    DRAIN_VM();                                                             \
    BAR();                                                                  \
  } while (0)

#define WIN_B(T, BO, OBO) do {                                              \
    if ((T) + 2 < NT) {                                                     \
      _Pragma("unroll") for (int j = 0; j < LA; ++j)                        \
        STAGE_A((T) + 2, BO, j);                                            \
      _Pragma("unroll") for (int j = 0; j < LB; ++j)                        \
        STAGE_B((T) + 2, BO, j);                                            \
    }                                                                       \
    if ((T) + 1 < NT) LDS_A0(OBO);                                          \
    QUAD(a1, MH, 0);                                                        \
    QUAD(a1, MH, 1);                                                        \
    DRAIN_LGKM();                                                           \
    BAR();                                                                  \
  } while (0)

  // prologue: stage tiles 0 and 1; certify tile 0; preload a0(0)
#pragma unroll
  for (int j = 0; j < LA; ++j) STAGE_A(0, 0, j);
#pragma unroll
  for (int j = 0; j < LB; ++j) STAGE_B(0, 0, j);
#pragma unroll
  for (int j = 0; j < LA; ++j) STAGE_A(1, BUF, j);
#pragma unroll
  for (int j = 0; j < LB; ++j) STAGE_B(1, BUF, j);
  asm volatile("s_waitcnt vmcnt(%0)" :: "n"(LA + LB) : "memory");
  BAR();
  LDS_A0(0);

  for (int T = 0; T < NT; T += 2) {
    WIN_A(T, 0);
    WIN_B(T, 0, BUF);
    WIN_A(T + 1, BUF);
    WIN_B(T + 1, BUF, 0);
  }

#undef WIN_A
#undef WIN_B
#undef QUAD
#undef LDS_A0
#undef LDS_A1
#undef LDS_B2
#undef STAGE_A
#undef STAGE_B
#undef BAR
#undef DRAIN_LGKM
#undef DRAIN_VM

  // epilogue
  const int orow0 = rowBase + wr * WROWS + (lane >> 4) * 4;
  const int ocol0 = colBase + wc * 64 + lr;
#pragma unroll
  for (int ni = 0; ni < 4; ++ni) {
    int n = ocol0 + ni * 16;
    float bv = bias[n];
    float th = 0.f, cc = 0.f;
    if constexpr (FUSED) { th = theta[n]; cc = c1[n]; }
#pragma unroll
    for (int mi = 0; mi < M_REP; ++mi) {
#pragma unroll
      for (int r = 0; r < 4; ++r) {
        size_t m = (size_t)(orow0 + mi * 16 + r);
        float h = acc[mi][ni][r] + bv;
        if constexpr (FUSED) {
          float q = h + cc * __sinf(th + 0.1f * h);
          ((unsigned short*)Cout)[m * N + n] = f2bf(fmaxf(q, 0.f));
        } else {
          ((float*)Cout)[m * N + n] = h;
        }
      }
    }
  }
}

// ---------------- launch ----------------

extern "C" void kernel_launch(void* const* d_in, const int* in_sizes, int n_in,
                              void* d_out, int out_size, void* d_ws,
                              size_t ws_size, hipStream_t stream) {
  const float* x     = (const float*)d_in[0];
  const float* W1    = (const float*)d_in[1];
  const float* b1    = (const float*)d_in[2];
  const float* theta = (const float*)d_in[3];
  const float* qwr   = (const float*)d_in[4];
  const float* qwi   = (const float*)d_in[5];
  const float* W2    = (const float*)d_in[6];
  const float* b2    = (const float*)d_in[7];
  float* out = (float*)d_out;

  const int M = 4 * 2048;            // 8192
  const int DM = 1024, DF = 4096;

  size_t need = ((size_t)96 << 20) + DF * sizeof(float);
  if (ws_size < need) return;

  char* ws = (char*)d_ws;
  unsigned short* xb   = (unsigned short*)ws;                          // 16 MiB
  unsigned short* w1t  = (unsigned short*)(ws + ((size_t)16 << 20));   //  8 MiB
  unsigned short* w2t  = (unsigned short*)(ws + ((size_t)24 << 20));   //  8 MiB
  unsigned short* actb = (unsigned short*)(ws + ((size_t)32 << 20));   // 64 MiB
  float* c1 = (float*)(ws + ((size_t)96 << 20));

  cvt_f32_bf16<<<2048, 256, 0, stream>>>(x, xb, M * DM / 4);
  transpose_cvt<<<dim3(DF / 32, DM / 32), 256, 0, stream>>>(W1, w1t, DM, DF);
  transpose_cvt<<<dim3(DM / 32, DF / 32), 256, 0, stream>>>(W2, w2t, DF, DM);
  qconst<<<DF / 256, 256, 0, stream>>>(theta, qwr, qwi, c1, DF);

  // GEMM1: 8192x4096, K=1024 -> 512 blocks (256x256 tile)
  gemmsk<256, 256, 16, true><<<512, 512, 0, stream>>>(
      xb, w1t, b1, theta, c1, (void*)actb, DF, DF / 256);
  // GEMM2: 8192x1024, K=4096 -> 256 blocks (128x256 tile)
  gemmsk<128, 256, 64, false><<<256, 512, 0, stream>>>(
      actb, w2t, b2, nullptr, nullptr, (void*)out, DM, DM / 256);
}